// Round 4
// baseline (1606.236 us; speedup 1.0000x reference)
//
#include <hip/hip_runtime.h>
#include <math.h>

// ============================================================================
// CapsNet forward, round 4 (= round 3 resubmit; infra timeout, never ran).
//   - conv2 via fp16 hi/lo split-K MFMA (3 passes: hh + hl + lh), REG-STAGED
//     LDS (no global_load_lds this round — isolate the round-2 crash).
//   - u_hat never materialized: routing passes recompute u from caps+W
//     (both cache-resident). Routing uses vsum linearity:
//     b_logit after iter k == u . (v0+..+v_{k-1}).
//   - Workspace: 250 MB (was 403 MB in the crashed round 2).
//
// Workspace (bytes):
//   ahi [0, 104857600)            alo [104857600, 209715200)
//   whi [209715200, 220332032)    wlo [220332032, 230948864)
//   caps[230948864, 249823232)
//   -- after conv2m, staging region is dead; alias small buffers at 0:
//   spart [0, 2949120)  vsum [2949120, +327680)  vbuf [3276800, +327680)
//   din [3604480, +327680)  h1 [3932160, +1048576)  h2 [4980736, +2097152)
// ============================================================================

typedef _Float16 f16x8 __attribute__((ext_vector_type(8)));
typedef float f32x4 __attribute__((ext_vector_type(4)));

// ---------------- conv1: x[512,1,28,28] -> relu -> ahi/alo[b][20][20][256] (x16)
__global__ __launch_bounds__(256) void k_conv1(const float* __restrict__ x,
        const float* __restrict__ w, const float* __restrict__ bias,
        _Float16* __restrict__ ahi, _Float16* __restrict__ alo) {
    __shared__ __align__(16) float xs[784];
    const int b = blockIdx.x;
    const int t = threadIdx.x;                     // = output channel ci
    for (int i = t; i < 784; i += 256) xs[i] = x[b * 784 + i];
    __syncthreads();

    float wr[81];
#pragma unroll
    for (int i = 0; i < 81; ++i) wr[i] = w[t * 81 + i];
    const float bv = bias[t];

    for (int oy = 0; oy < 20; ++oy) {
        float acc[20];
#pragma unroll
        for (int px = 0; px < 20; ++px) acc[px] = bv;
#pragma unroll
        for (int ky = 0; ky < 9; ++ky) {
            const float* xrow = &xs[(oy + ky) * 28];
            float xr[28];
#pragma unroll
            for (int j = 0; j < 7; ++j) {
                float4 v4 = *(const float4*)(xrow + j * 4);
                xr[j * 4 + 0] = v4.x; xr[j * 4 + 1] = v4.y;
                xr[j * 4 + 2] = v4.z; xr[j * 4 + 3] = v4.w;
            }
#pragma unroll
            for (int kx = 0; kx < 9; ++kx) {
                const float wv = wr[ky * 9 + kx];
#pragma unroll
                for (int px = 0; px < 20; ++px)
                    acc[px] = fmaf(wv, xr[px + kx], acc[px]);
            }
        }
#pragma unroll
        for (int px = 0; px < 20; ++px) {
            const float v16 = fmaxf(acc[px], 0.f) * 16.f;
            const _Float16 hi = (_Float16)v16;
            const _Float16 lo = (_Float16)(v16 - (float)hi);
            const int idx = (b * 400 + oy * 20 + px) * 256 + t;
            ahi[idx] = hi;
            alo[idx] = lo;
        }
    }
}

// ---------------- W2 convert: pc_w[n][ci][tap] -> whi/wlo[n][tap*256+ci] (x16)
__global__ __launch_bounds__(256) void k_wcvt(const float* __restrict__ w2,
        _Float16* __restrict__ whi, _Float16* __restrict__ wlo) {
    const int i = blockIdx.x * 256 + threadIdx.x;  // 5,308,416 outputs
    const int n = i / 20736;
    const int r = i - n * 20736;
    const int tap = r >> 8;
    const int ci = r & 255;
    const float v = w2[(n * 256 + ci) * 81 + tap] * 16.f;
    const _Float16 hi = (_Float16)v;
    whi[i] = hi;
    wlo[i] = (_Float16)(v - (float)hi);
}

// ---------------- conv2 MFMA implicit GEMM (reg-staged LDS)
// C[m,n] = (1/256) sum_k A[m,k]*W[n,k] + bias[n], K = 81*256 (tap-major, ci contig)
// A[m,(tap,ci)] = ht[b, 2oy+ky, 2ox+kx, ci], m = b*36 + oy*6 + ox.
// Tile BM=64 BN=128 BK=64, 256 thr (4 waves, 2x2 wave grid, wave tile 32x64).
// Staging: global -> f16x8 regs (swizzled source addr) -> linear ds_write_b128
// (conflict-free). Reads use oct' = oct ^ (row&7) -> 2-way aliasing (free).
__global__ __launch_bounds__(256, 3) void k_conv2m(
        const _Float16* __restrict__ ahi, const _Float16* __restrict__ alo,
        const _Float16* __restrict__ whi, const _Float16* __restrict__ wlo,
        const float* __restrict__ bias, float* __restrict__ p) {
    __shared__ __align__(16) _Float16 lds[24576];  // 48 KB
    _Float16* sAhi = lds;                          // [64 rows][64 k]
    _Float16* sAlo = lds + 4096;
    _Float16* sBhi = lds + 8192;                   // [128 rows][64 k]
    _Float16* sBlo = lds + 16384;

    const int t = threadIdx.x;
    const int l = t & 63, w = t >> 6;
    const int m0 = blockIdx.x * 64;
    const int n0 = blockIdx.y * 128;

    // staging geometry: issue block (i*4+w) covers rows (i*4+w)*8 + (l>>3),
    // lane writes LDS linearly at slot l*8; source col = (l&7 ^ l>>3)*8.
    const int sr = l >> 3;                         // 0..7
    const int oct = ((l & 7) ^ sr) * 8;            // swizzled source ci-offset
    int apix[2];
#pragma unroll
    for (int i = 0; i < 2; ++i) {
        const int r = w * 8 + sr + i * 32;         // A row 0..63
        const int m = m0 + r;
        const int b = m / 36, pix = m - b * 36;
        const int oy = pix / 6, ox = pix - oy * 6;
        apix[i] = (b * 400 + oy * 40 + ox * 2) * 256 + oct;
    }
    int wbase[4];
#pragma unroll
    for (int i = 0; i < 4; ++i) {
        const int nr = (i * 4 + w) * 8 + sr;       // B row 0..127
        wbase[i] = (n0 + nr) * 20736 + oct;
    }

    f32x4 acc[2][4];
#pragma unroll
    for (int mf = 0; mf < 2; ++mf)
#pragma unroll
        for (int nf = 0; nf < 4; ++nf) acc[mf][nf] = (f32x4){0.f, 0.f, 0.f, 0.f};

    const int wm = (w >> 1) * 32, wn = (w & 1) * 64;
    const int lm = l & 15, lk = l >> 4;

    f16x8 rAh[2], rAl[2], rBh[4], rBl[4];
    int ky = 0, kx = 0, ci0 = 0, k0 = 0;           // load cursor

#define C2_LOAD() do { \
        const int koff = (ky * 20 + kx) * 256 + ci0; \
        rAh[0] = *(const f16x8*)(ahi + apix[0] + koff); \
        rAl[0] = *(const f16x8*)(alo + apix[0] + koff); \
        rAh[1] = *(const f16x8*)(ahi + apix[1] + koff); \
        rAl[1] = *(const f16x8*)(alo + apix[1] + koff); \
        _Pragma("unroll") \
        for (int i = 0; i < 4; ++i) { \
            rBh[i] = *(const f16x8*)(whi + wbase[i] + k0); \
            rBl[i] = *(const f16x8*)(wlo + wbase[i] + k0); \
        } \
        ci0 += 64; k0 += 64; \
        if (ci0 == 256) { ci0 = 0; ++kx; if (kx == 9) { kx = 0; ++ky; } } \
    } while (0)

    C2_LOAD();                                     // preload step 0

    for (int step = 0; step < 324; ++step) {
        __syncthreads();                           // prev readers done with LDS
#pragma unroll
        for (int i = 0; i < 2; ++i) {
            *(f16x8*)(sAhi + (i * 4 + w) * 512 + l * 8) = rAh[i];
            *(f16x8*)(sAlo + (i * 4 + w) * 512 + l * 8) = rAl[i];
        }
#pragma unroll
        for (int i = 0; i < 4; ++i) {
            *(f16x8*)(sBhi + (i * 4 + w) * 512 + l * 8) = rBh[i];
            *(f16x8*)(sBlo + (i * 4 + w) * 512 + l * 8) = rBl[i];
        }
        __syncthreads();                           // tile visible to all waves
        if (step < 323) C2_LOAD();                 // prefetch hides under MFMA

#pragma unroll
        for (int ks = 0; ks < 2; ++ks) {
            const int oj = ks * 4 + lk;            // k-oct 0..7
            f16x8 afh[2], afl[2];
#pragma unroll
            for (int mf = 0; mf < 2; ++mf) {
                const int row = wm + mf * 16 + lm;
                const int off = row * 64 + (oj ^ (lm & 7)) * 8;
                afh[mf] = *(const f16x8*)&sAhi[off];
                afl[mf] = *(const f16x8*)&sAlo[off];
            }
#pragma unroll
            for (int nf = 0; nf < 4; ++nf) {
                const int row = wn + nf * 16 + lm;
                const int off = row * 64 + (oj ^ (lm & 7)) * 8;
                const f16x8 bh = *(const f16x8*)&sBhi[off];
                const f16x8 bl = *(const f16x8*)&sBlo[off];
#pragma unroll
                for (int mf = 0; mf < 2; ++mf) {
                    acc[mf][nf] = __builtin_amdgcn_mfma_f32_16x16x32_f16(
                        afh[mf], bh, acc[mf][nf], 0, 0, 0);
                    acc[mf][nf] = __builtin_amdgcn_mfma_f32_16x16x32_f16(
                        afh[mf], bl, acc[mf][nf], 0, 0, 0);
                    acc[mf][nf] = __builtin_amdgcn_mfma_f32_16x16x32_f16(
                        afl[mf], bh, acc[mf][nf], 0, 0, 0);
                }
            }
        }
    }
#undef C2_LOAD

    // epilogue: D col(n) = l&15, row(m) = (l>>4)*4 + r
#pragma unroll
    for (int nf = 0; nf < 4; ++nf) {
        const int n = n0 + wn + nf * 16 + lm;
        const float bv = bias[n];
#pragma unroll
        for (int mf = 0; mf < 2; ++mf) {
#pragma unroll
            for (int r = 0; r < 4; ++r) {
                const int m = m0 + wm + mf * 16 + lk * 4 + r;
                const int b = m / 36, pix = m - b * 36;
                p[(b * 256 + n) * 36 + pix] = acc[mf][nf][r] * (1.f / 256.f) + bv;
            }
        }
    }
}

// ---------------- squash caps in place: [512*1152][8]
__global__ __launch_bounds__(256) void k_squash(float* __restrict__ pc) {
    const long long i = (long long)blockIdx.x * 256 + threadIdx.x;  // 589824
    float* p = pc + i * 8;
    float4 v0 = *(float4*)p;
    float4 v1 = *(float4*)(p + 4);
    const float sq = v0.x * v0.x + v0.y * v0.y + v0.z * v0.z + v0.w * v0.w
                   + v1.x * v1.x + v1.y * v1.y + v1.z * v1.z + v1.w * v1.w;
    const float sc = (sq / (1.f + sq)) / (sqrtf(sq) + 1e-8f);
    v0.x *= sc; v0.y *= sc; v0.z *= sc; v0.w *= sc;
    v1.x *= sc; v1.y *= sc; v1.z *= sc; v1.w *= sc;
    *(float4*)p = v0;
    *(float4*)(p + 4) = v1;
}

// ---------------- fused routing pass (u_hat recomputed on the fly):
// u[o] = dot8(W[o,n,d,:], caps[b,n,:]);
// c = 0.1 (uniform) or softmax_o( sum_d u[o]*vsum[b,o,d] );
// sp[b,nc,o,d] = sum_{n in chunk} c[o] * u[o]
// grid (512, 9), block 128: thread = (g = t>>4 in [0,8), d = t&15); 16 n each.
__global__ __launch_bounds__(128) void k_route(const float* __restrict__ caps,
        const float* __restrict__ W, const float* __restrict__ vsum,
        float* __restrict__ sp, int uniform) {
    const int b = blockIdx.x, nc = blockIdx.y;
    const int t = threadIdx.x;
    const int d = t & 15, g = t >> 4;
    __shared__ float vs[160];
    __shared__ float red[2][160];
    if (uniform == 0)
        for (int i = t; i < 160; i += 128) vs[i] = vsum[b * 160 + i];
    __syncthreads();

    float sacc[10];
#pragma unroll
    for (int o = 0; o < 10; ++o) sacc[o] = 0.f;

    for (int i = 0; i < 16; ++i) {
        const int n = nc * 128 + i * 8 + g;
        const float* cp = caps + ((long long)b * 1152 + n) * 8;
        const float4 ca = *(const float4*)cp;
        const float4 cb = *(const float4*)(cp + 4);
        float uv[10];
#pragma unroll
        for (int o = 0; o < 10; ++o) {
            const float* wp = W + (((long long)o * 1152 + n) * 16 + d) * 8;
            const float4 wa = *(const float4*)wp;
            const float4 wb = *(const float4*)(wp + 4);
            float s = wa.x * ca.x;
            s = fmaf(wa.y, ca.y, s); s = fmaf(wa.z, ca.z, s); s = fmaf(wa.w, ca.w, s);
            s = fmaf(wb.x, cb.x, s); s = fmaf(wb.y, cb.y, s); s = fmaf(wb.z, cb.z, s);
            s = fmaf(wb.w, cb.w, s);
            uv[o] = s;
        }
        float c[10];
        if (uniform) {
#pragma unroll
            for (int o = 0; o < 10; ++o) c[o] = 0.1f;
        } else {
            float dot[10];
#pragma unroll
            for (int o = 0; o < 10; ++o) {
                float xx = uv[o] * vs[o * 16 + d];
                xx += __shfl_xor(xx, 1);
                xx += __shfl_xor(xx, 2);
                xx += __shfl_xor(xx, 4);
                xx += __shfl_xor(xx, 8);
                dot[o] = xx;
            }
            float mx = dot[0];
#pragma unroll
            for (int o = 1; o < 10; ++o) mx = fmaxf(mx, dot[o]);
            float sum = 0.f;
#pragma unroll
            for (int o = 0; o < 10; ++o) { c[o] = expf(dot[o] - mx); sum += c[o]; }
            const float inv = 1.f / sum;
#pragma unroll
            for (int o = 0; o < 10; ++o) c[o] *= inv;
        }
#pragma unroll
        for (int o = 0; o < 10; ++o) sacc[o] = fmaf(c[o], uv[o], sacc[o]);
    }
    // reduce over g: lane bits 4,5 within wave, then across the 2 waves
#pragma unroll
    for (int o = 0; o < 10; ++o) {
        sacc[o] += __shfl_xor(sacc[o], 16);
        sacc[o] += __shfl_xor(sacc[o], 32);
    }
    const int wv = t >> 6;
    if ((t & 63) < 16) {
#pragma unroll
        for (int o = 0; o < 10; ++o) red[wv][o * 16 + d] = sacc[o];
    }
    __syncthreads();
    for (int i = t; i < 160; i += 128)
        sp[((long long)(b * 9 + nc)) * 160 + i] = red[0][i] + red[1][i];
}

// ---------------- v = squash(sum_ch sp); vsum = first ? v : vsum + v; vbuf = v
__global__ __launch_bounds__(160) void k_squashv(const float* __restrict__ sp,
        float* __restrict__ vsum, float* __restrict__ vbuf, int first) {
    const int b = blockIdx.x, t = threadIdx.x;     // t = o*16+d
    float s = 0.f;
#pragma unroll
    for (int ch = 0; ch < 9; ++ch) s += sp[((long long)(b * 9 + ch)) * 160 + t];
    float sq = s * s;
    sq += __shfl_xor(sq, 1);
    sq += __shfl_xor(sq, 2);
    sq += __shfl_xor(sq, 4);
    sq += __shfl_xor(sq, 8);
    const float sc = (sq / (1.f + sq)) / (sqrtf(sq) + 1e-8f);
    const float v = s * sc;
    vbuf[b * 160 + t] = v;
    vsum[b * 160 + t] = first ? v : (vsum[b * 160 + t] + v);
}

// ---------------- logits = ||v||, dec_in = v * onehot(argmax)
__global__ __launch_bounds__(64) void k_logits(const float* __restrict__ v,
        float* __restrict__ logits, float* __restrict__ dec_in) {
    const int b = blockIdx.x * 64 + threadIdx.x;   // 512
    const float* vp = v + (long long)b * 160;
    float nrm[10];
    int amax = 0;
    float best = -1.f;
#pragma unroll
    for (int o = 0; o < 10; ++o) {
        float s = 0.f;
#pragma unroll
        for (int dd = 0; dd < 16; ++dd) { const float xv = vp[o * 16 + dd]; s = fmaf(xv, xv, s); }
        nrm[o] = sqrtf(s);
        if (nrm[o] > best) { best = nrm[o]; amax = o; }  // first max wins
    }
#pragma unroll
    for (int o = 0; o < 10; ++o) logits[b * 10 + o] = nrm[o];
#pragma unroll
    for (int o = 0; o < 10; ++o)
#pragma unroll
        for (int dd = 0; dd < 16; ++dd)
            dec_in[(long long)b * 160 + o * 16 + dd] = (o == amax) ? vp[o * 16 + dd] : 0.f;
}

// ---------------- dense GEMM: C[M,N] = act(A[M,K] @ W[N,K]^T + bias)
template <int ACT>
__global__ __launch_bounds__(256) void k_gemm(const float* __restrict__ A,
        const float* __restrict__ W, const float* __restrict__ bias,
        float* __restrict__ C, int N, int K) {
    __shared__ float As[16][68];
    __shared__ float Bs[16][68];
    const int m0 = blockIdx.x * 64, n0 = blockIdx.y * 64;
    const int t = threadIdx.x;
    const int kl = t & 15, rr = t >> 4;
    const int tm = t & 15, tn = t >> 4;

    float acc[4][4];
#pragma unroll
    for (int i = 0; i < 4; ++i)
#pragma unroll
        for (int j = 0; j < 4; ++j) acc[i][j] = 0.f;

    for (int k0 = 0; k0 < K; k0 += 16) {
#pragma unroll
        for (int i = 0; i < 4; ++i) {
            As[kl][rr + i * 16] = A[(m0 + rr + i * 16) * K + k0 + kl];
            const int n = n0 + rr + i * 16;
            Bs[kl][rr + i * 16] = (n < N) ? W[(long long)n * K + k0 + kl] : 0.f;
        }
        __syncthreads();
#pragma unroll
        for (int kk = 0; kk < 16; ++kk) {
            float a[4], bb[4];
#pragma unroll
            for (int i = 0; i < 4; ++i) a[i] = As[kk][tm * 4 + i];
#pragma unroll
            for (int j = 0; j < 4; ++j) bb[j] = Bs[kk][tn * 4 + j];
#pragma unroll
            for (int i = 0; i < 4; ++i)
#pragma unroll
                for (int j = 0; j < 4; ++j)
                    acc[i][j] = fmaf(a[i], bb[j], acc[i][j]);
        }
        __syncthreads();
    }
#pragma unroll
    for (int j = 0; j < 4; ++j) {
        const int n = n0 + tn * 4 + j;
        if (n < N) {
            const float bv = bias[n];
#pragma unroll
            for (int i = 0; i < 4; ++i) {
                const int m = m0 + tm * 4 + i;
                float xv = acc[i][j] + bv;
                if (ACT == 0) xv = fmaxf(xv, 0.f);
                else          xv = 1.f / (1.f + expf(-xv));
                C[(long long)m * N + n] = xv;
            }
        }
    }
}

// ============================================================================
extern "C" void kernel_launch(void* const* d_in, const int* in_sizes, int n_in,
                              void* d_out, int out_size, void* d_ws, size_t ws_size,
                              hipStream_t stream) {
    const float* x      = (const float*)d_in[0];
    const float* conv_w = (const float*)d_in[1];
    const float* conv_b = (const float*)d_in[2];
    const float* pc_w   = (const float*)d_in[3];
    const float* pc_b   = (const float*)d_in[4];
    const float* Wrt    = (const float*)d_in[5];
    const float* dw1    = (const float*)d_in[6];
    const float* db1    = (const float*)d_in[7];
    const float* dw2    = (const float*)d_in[8];
    const float* db2    = (const float*)d_in[9];
    const float* dw3    = (const float*)d_in[10];
    const float* db3    = (const float*)d_in[11];

    float* out = (float*)d_out;                 // [0,5120) logits, then recon
    char* wsb  = (char*)d_ws;

    _Float16* ahi = (_Float16*)(wsb);                 // 104,857,600 B
    _Float16* alo = (_Float16*)(wsb + 104857600);
    _Float16* whi = (_Float16*)(wsb + 209715200);     // 10,616,832 B
    _Float16* wlo = (_Float16*)(wsb + 220332032);
    float* caps = (float*)(wsb + 230948864);          // 18,874,368 B
    // staging region dead after conv2m -> alias small buffers at offset 0
    float* spart= (float*)(wsb);                      // 2,949,120 B
    float* vsum = (float*)(wsb + 2949120);
    float* vbuf = (float*)(wsb + 3276800);
    float* din  = (float*)(wsb + 3604480);
    float* h1   = (float*)(wsb + 3932160);
    float* h2   = (float*)(wsb + 4980736);
    // total ws use: 249,823,232 bytes

    k_conv1<<<512, 256, 0, stream>>>(x, conv_w, conv_b, ahi, alo);
    k_wcvt<<<20736, 256, 0, stream>>>(pc_w, whi, wlo);
    k_conv2m<<<dim3(288, 2), 256, 0, stream>>>(ahi, alo, whi, wlo, pc_b, caps);
    k_squash<<<2304, 256, 0, stream>>>(caps);

    // routing via vsum linearity: b_logit after iter k == u . (v0+..+v_{k-1})
    k_route<<<dim3(512, 9), 128, 0, stream>>>(caps, Wrt, vsum, spart, 1);
    k_squashv<<<512, 160, 0, stream>>>(spart, vsum, vbuf, 1);   // vsum = v0
    k_route<<<dim3(512, 9), 128, 0, stream>>>(caps, Wrt, vsum, spart, 0);
    k_squashv<<<512, 160, 0, stream>>>(spart, vsum, vbuf, 0);   // vsum = v0+v1
    k_route<<<dim3(512, 9), 128, 0, stream>>>(caps, Wrt, vsum, spart, 0);
    k_squashv<<<512, 160, 0, stream>>>(spart, vsum, vbuf, 0);   // vbuf = v2

    k_logits<<<8, 64, 0, stream>>>(vbuf, out, din);

    k_gemm<0><<<dim3(8, 8),  256, 0, stream>>>(din, dw1, db1, h1, 512, 160);
    k_gemm<0><<<dim3(8, 16), 256, 0, stream>>>(h1,  dw2, db2, h2, 1024, 512);
    k_gemm<1><<<dim3(8, 13), 256, 0, stream>>>(h2,  dw3, db3, out + 5120, 784, 1024);
}